// Round 1
// baseline (436.880 us; speedup 1.0000x reference)
//
#include <hip/hip_runtime.h>
#include <math.h>

#define NROWS 262144
#define DIM   256
#define NC    64
#define CD    (NC*DIM)       // 16384 floats = 64 KB
#define T1    512
#define MAXP  512

// ws float-offset layout:
//  A: acc_cent  [CD]    @ 0       (atomic-fallback accumulator)
//  B: s_part    [4096]  @ 16384   (64 slot-groups x 64 classes, atomics)
//  C: cent_new  [CD]    @ 20480   (K2 output, linear [c][d])
//  D: s_final   [64]    @ 36864
//  E: abs_part  [256]   @ 36928
//  F: pair_part [64]    @ 37184
//  G: partials  [P*CD]  @ 37248
#define OFF_S     16384
#define OFF_CENT  20480
#define OFF_SF    36864
#define OFF_ABS   36928
#define OFF_PAIR  37184
#define OFF_PART  37248

__global__ __launch_bounds__(T1)
void k1_main(const float* __restrict__ pred, const float* __restrict__ cent,
             const float* __restrict__ count, const int* __restrict__ tgt,
             float* __restrict__ ws, int P)
{
    __shared__ float sp[CD];
    const int tid = threadIdx.x;
    for (int o = tid; o < CD; o += T1) sp[o] = 0.f;
    __syncthreads();

    const int lane = tid & 63;
    const int wid  = tid >> 6;
    const int nw   = gridDim.x * (T1 / 64);
    const int gw   = blockIdx.x * (T1 / 64) + wid;
    const int chunk = (NROWS + nw - 1) / nw;
    int r0 = gw * chunk;
    int r1 = r0 + chunk; if (r1 > NROWS) r1 = NROWS;

    const float4* pred4 = (const float4*)pred;
    const float4* cent4 = (const float4*)cent;
    float* s_slot = ws + OFF_S + (blockIdx.x & 63) * NC;

    #pragma unroll 2
    for (int r = r0; r < r1; ++r) {
        int   c   = tgt[r];
        float inv = 1.0f / count[c];
        float4 p  = pred4[r * 64 + lane];
        float4 ce = cent4[c * 64 + lane];
        float dx = ce.x - p.x * inv;
        float dy = ce.y - p.y * inv;
        float dz = ce.z - p.z * inv;
        float dw = ce.w - p.w * inv;
        float ss = dx*dx + dy*dy + dz*dz + dw*dw;
        #pragma unroll
        for (int o = 32; o > 0; o >>= 1) ss += __shfl_xor(ss, o, 64);
        // transposed layout: element d = 4*lane + k stored at c*256 + k*64 + lane
        int base = c * 256 + lane;
        unsafeAtomicAdd(&sp[base      ], p.x);
        unsafeAtomicAdd(&sp[base +  64], p.y);
        unsafeAtomicAdd(&sp[base + 128], p.z);
        unsafeAtomicAdd(&sp[base + 192], p.w);
        if (lane == 0) unsafeAtomicAdd(&s_slot[c], sqrtf(ss));
    }
    __syncthreads();

    if (P > 0) {
        float* dst = ws + OFF_PART + (size_t)blockIdx.x * CD;
        for (int o = tid; o < CD; o += T1) dst[o] = sp[o];
    } else {
        for (int o = tid; o < CD; o += T1) unsafeAtomicAdd(&ws[o], sp[o]);
    }
}

__global__ __launch_bounds__(256)
void k2_reduce(const float* __restrict__ cent, const float* __restrict__ count,
               const float* __restrict__ dist, float* __restrict__ ws, int P)
{
    const int tid = threadIdx.x;
    const int sub = tid & 63;       // offset within this block's 64 elements
    const int g   = tid >> 6;       // 0..3 partial-group
    const int o   = blockIdx.x * 64 + sub;   // 0..16383

    float sum = 0.f;
    if (P > 0) {
        const float* gp = ws + OFF_PART;
        for (int p = g; p < P; p += 4) sum += gp[(size_t)p * CD + o];
    } else if (g == 0) {
        sum = ws[o];
    }
    __shared__ float red[4][64];
    red[g][sub] = sum;
    __syncthreads();

    if (tid < 64) {
        float tot = red[0][tid] + red[1][tid] + red[2][tid] + red[3][tid];
        int oo = blockIdx.x * 64 + tid;
        int c = oo >> 8, rr = oo & 255, k = rr >> 6, l = rr & 63;
        int d = 4 * l + k;
        float val = cent[c * 256 + d] + tot / count[c];
        ws[OFF_CENT + c * 256 + d] = val;
        float a = fabsf(val);
        #pragma unroll
        for (int off = 32; off > 0; off >>= 1) a += __shfl_xor(a, off, 64);
        if (tid == 0) ws[OFF_ABS + blockIdx.x] = a;
    }
    if (blockIdx.x == 0 && tid < NC) {
        float ssum = 0.f;
        for (int g2 = 0; g2 < 64; ++g2) ssum += ws[OFF_S + g2 * NC + tid];
        ws[OFF_SF + tid] = sqrtf(dist[tid] + ssum) / count[tid];
    }
}

__global__ __launch_bounds__(256)
void k3_pairs(const float* __restrict__ cw, float* __restrict__ ws)
{
    const int i    = blockIdx.x;
    const int tid  = threadIdx.x;
    const int lane = tid & 63;
    const int w    = tid >> 6;
    const float4* c4 = (const float4*)(ws + OFF_CENT);
    const float*  sf = ws + OFF_SF;

    float4 ci = c4[i * 64 + lane];
    float  si = sf[i];
    float acc = 0.f;
    for (int j = w; j < NC; j += 4) {
        if (j == i) continue;
        float4 cj = c4[j * 64 + lane];
        float dx = ci.x - cj.x, dy = ci.y - cj.y;
        float dz = ci.z - cj.z, dw = ci.w - cj.w;
        float ss = dx*dx + dy*dy + dz*dz + dw*dw;
        #pragma unroll
        for (int o = 32; o > 0; o >>= 1) ss += __shfl_xor(ss, o, 64);
        float m = sqrtf(ss);
        acc += cw[i * NC + j] * (si + sf[j]) / m;
    }
    __shared__ float wsum[4];
    if (lane == 0) wsum[w] = acc;
    __syncthreads();
    if (tid == 0) ws[OFF_PAIR + i] = wsum[0] + wsum[1] + wsum[2] + wsum[3];
}

__global__ __launch_bounds__(256)
void k4_final(const float* __restrict__ ws, float* __restrict__ out)
{
    const int t = threadIdx.x;   // 256 threads
    float a = ws[OFF_ABS + t];
    float p = (t < 64) ? ws[OFF_PAIR + t] : 0.f;
    #pragma unroll
    for (int o = 32; o > 0; o >>= 1) {
        a += __shfl_xor(a, o, 64);
        p += __shfl_xor(p, o, 64);
    }
    __shared__ float ra[4], rp[4];
    if ((t & 63) == 0) { ra[t >> 6] = a; rp[t >> 6] = p; }
    __syncthreads();
    if (t == 0) {
        float pair_sum = rp[0] + rp[1] + rp[2] + rp[3];
        float abs_sum  = ra[0] + ra[1] + ra[2] + ra[3];
        out[0] = pair_sum / 64.0f * 63.0f + abs_sum * 1e-6f;
    }
}

extern "C" void kernel_launch(void* const* d_in, const int* in_sizes, int n_in,
                              void* d_out, int out_size, void* d_ws, size_t ws_size,
                              hipStream_t stream)
{
    const float* pred  = (const float*)d_in[0];
    const float* cent  = (const float*)d_in[1];
    const float* dist  = (const float*)d_in[2];
    const float* count = (const float*)d_in[3];
    const float* cw    = (const float*)d_in[4];
    const int*   tgt   = (const int*)d_in[5];
    float* ws  = (float*)d_ws;
    float* out = (float*)d_out;

    long ws_f  = (long)(ws_size / sizeof(float));
    long avail = ws_f - OFF_PART;
    int P = 0;
    if (avail >= 64L * CD) {
        long p = avail / CD;
        P = (int)(p < MAXP ? p : MAXP);
    }
    int grid1 = (P > 0) ? P : 512;

    // zero the atomic regions (A + B)
    hipMemsetAsync(d_ws, 0, (size_t)(CD + 4096) * sizeof(float), stream);

    k1_main<<<grid1, T1, 0, stream>>>(pred, cent, count, tgt, ws, P);
    k2_reduce<<<256, 256, 0, stream>>>(cent, count, dist, ws, P);
    k3_pairs<<<NC, 256, 0, stream>>>(cw, ws);
    k4_final<<<1, 256, 0, stream>>>(ws, out);
}

// Round 2
// 385.897 us; speedup vs baseline: 1.1321x; 1.1321x over previous
//
#include <hip/hip_runtime.h>
#include <math.h>

#define NROWS 262144
#define DIM   256
#define NC    64
#define CD    (NC*DIM)       // 16384 floats = 64 KB
#define T1    512
#define NBLK  512

// ws float-offset layout:
//  A: acc fallback [CD]      @ 0
//  B: s_part [NBLK*64]       @ 16384
//  C: cent_new [CD]          @ 49152
//  D: s_final [64]           @ 65536
//  E: abs_part [256]         @ 65600
//  F: pair_part [64]         @ 65856
//  G: partials [P*CD]        @ 65920
#define OFF_S     16384
#define OFF_CENT  49152
#define OFF_SF    65536
#define OFF_ABS   65600
#define OFF_PAIR  65856
#define OFF_PART  65920

__global__ __launch_bounds__(T1, 4)
void k1_main(const float* __restrict__ pred, const float* __restrict__ cent,
             const float* __restrict__ count, const int* __restrict__ tgt,
             float* __restrict__ ws, int P)
{
    __shared__ float acc[CD];
    const int tid = threadIdx.x;
    for (int o = tid; o < CD; o += T1) acc[o] = 0.f;

    const int lane = tid & 63;
    const int wid  = tid >> 6;
    const int l16  = lane & 15;
    const int sub  = lane >> 4;

    const int r0 = (blockIdx.x * 8 + wid) * 64;   // 64 rows per wave
    const int   t_reg   = tgt[r0 + lane];         // this wave's 64 targets
    const float inv_reg = 1.0f / count[lane];     // 1/count for class 'lane'

    __syncthreads();

    const float4* pred4 = (const float4*)pred;
    const float4* cent4 = (const float4*)cent;
    float* s_blk = ws + OFF_S + blockIdx.x * 64;  // block-private s region

    #pragma unroll 2
    for (int i = 0; i < 16; ++i) {
        const int rowq = 4 * i + sub;                   // row handled by this 16-lane group
        const int c    = __shfl(t_reg, rowq, 64);       // class of my row
        const float inv = __shfl(inv_reg, c, 64);       // 1/count[c]

        const float4* prow = pred4 + (size_t)(r0 + rowq) * 64 + l16;
        const float4* crow = cent4 + (size_t)c * 64 + l16;
        float4 p0 = prow[0],  p1 = prow[16], p2 = prow[32], p3 = prow[48];
        float4 e0 = crow[0],  e1 = crow[16], e2 = crow[32], e3 = crow[48];

        float4 pr0, pr1, pr2, pr3;
        float ss = 0.f, d;
        pr0.x = p0.x*inv; d = e0.x-pr0.x; ss += d*d;
        pr0.y = p0.y*inv; d = e0.y-pr0.y; ss += d*d;
        pr0.z = p0.z*inv; d = e0.z-pr0.z; ss += d*d;
        pr0.w = p0.w*inv; d = e0.w-pr0.w; ss += d*d;
        pr1.x = p1.x*inv; d = e1.x-pr1.x; ss += d*d;
        pr1.y = p1.y*inv; d = e1.y-pr1.y; ss += d*d;
        pr1.z = p1.z*inv; d = e1.z-pr1.z; ss += d*d;
        pr1.w = p1.w*inv; d = e1.w-pr1.w; ss += d*d;
        pr2.x = p2.x*inv; d = e2.x-pr2.x; ss += d*d;
        pr2.y = p2.y*inv; d = e2.y-pr2.y; ss += d*d;
        pr2.z = p2.z*inv; d = e2.z-pr2.z; ss += d*d;
        pr2.w = p2.w*inv; d = e2.w-pr2.w; ss += d*d;
        pr3.x = p3.x*inv; d = e3.x-pr3.x; ss += d*d;
        pr3.y = p3.y*inv; d = e3.y-pr3.y; ss += d*d;
        pr3.z = p3.z*inv; d = e3.z-pr3.z; ss += d*d;
        pr3.w = p3.w*inv; d = e3.w-pr3.w; ss += d*d;

        // reduce ss within the 16-lane group (4 rows reduce simultaneously)
        ss += __shfl_xor(ss, 1, 64);
        ss += __shfl_xor(ss, 2, 64);
        ss += __shfl_xor(ss, 4, 64);
        ss += __shfl_xor(ss, 8, 64);

        if (l16 == 0) unsafeAtomicAdd(&s_blk[c], sqrtf(ss));

        // accumulate pr into LDS, storage idx = c*256 + ((q*4+k)^ (c&15))*16 + l16
        const int cb = c * 256 + l16;
        const int cx = c & 15;
        #define ACCADD(q, k, v) unsafeAtomicAdd(&acc[cb + (((((q)<<2)|(k)) ^ cx) << 4)], v)
        ACCADD(0,0,pr0.x); ACCADD(0,1,pr0.y); ACCADD(0,2,pr0.z); ACCADD(0,3,pr0.w);
        ACCADD(1,0,pr1.x); ACCADD(1,1,pr1.y); ACCADD(1,2,pr1.z); ACCADD(1,3,pr1.w);
        ACCADD(2,0,pr2.x); ACCADD(2,1,pr2.y); ACCADD(2,2,pr2.z); ACCADD(2,3,pr2.w);
        ACCADD(3,0,pr3.x); ACCADD(3,1,pr3.y); ACCADD(3,2,pr3.z); ACCADD(3,3,pr3.w);
        #undef ACCADD
    }
    __syncthreads();

    if (P > 0) {
        float* dst = ws + OFF_PART + (size_t)blockIdx.x * CD;
        for (int o = tid; o < CD; o += T1) dst[o] = acc[o];
    } else {
        for (int o = tid; o < CD; o += T1) unsafeAtomicAdd(&ws[o], acc[o]);
    }
}

__global__ __launch_bounds__(256)
void k2_reduce(const float* __restrict__ cent, const float* __restrict__ count,
               const float* __restrict__ dist, float* __restrict__ ws, int P)
{
    const int tid = threadIdx.x;
    const int sub = tid & 63;
    const int g   = tid >> 6;                 // 0..3
    const int o   = blockIdx.x * 64 + sub;    // storage index 0..16383

    float sum = 0.f;
    if (P > 0) {
        const float* gp = ws + OFF_PART;
        #pragma unroll 4
        for (int p = g; p < P; p += 4) sum += gp[(size_t)p * CD + o];
    } else if (g == 0) {
        sum = ws[o];
    }
    __shared__ float red[4][64];
    red[g][sub] = sum;
    __syncthreads();

    if (tid < 64) {
        float tot = red[0][tid] + red[1][tid] + red[2][tid] + red[3][tid];
        const int oo   = blockIdx.x * 64 + tid;
        const int c    = oo >> 8;
        const int sidx = oo & 255;
        const int grp  = sidx >> 4, l = sidx & 15;
        const int qk   = grp ^ (c & 15);
        const int dd   = (qk >> 2) * 64 + l * 4 + (qk & 3);
        float val = cent[c * 256 + dd] + tot;           // tot is sum of pr already
        ws[OFF_CENT + c * 256 + dd] = val;
        float a = fabsf(val);
        #pragma unroll
        for (int off = 32; off > 0; off >>= 1) a += __shfl_xor(a, off, 64);
        if (tid == 0) ws[OFF_ABS + blockIdx.x] = a;
    }

    if (blockIdx.x == 0) {
        __shared__ float sred[4][64];
        float ssum = 0.f;
        #pragma unroll 4
        for (int b = g; b < NBLK; b += 4) ssum += ws[OFF_S + b * 64 + sub];
        sred[g][sub] = ssum;
        __syncthreads();
        if (tid < 64) {
            float s_tot = sred[0][tid] + sred[1][tid] + sred[2][tid] + sred[3][tid];
            ws[OFF_SF + tid] = sqrtf(dist[tid] + s_tot) / count[tid];
        }
    }
}

__global__ __launch_bounds__(256)
void k3_pairs(const float* __restrict__ cw, float* __restrict__ ws)
{
    const int i    = blockIdx.x;
    const int tid  = threadIdx.x;
    const int lane = tid & 63;
    const int w    = tid >> 6;
    const float4* c4 = (const float4*)(ws + OFF_CENT);
    const float*  sf = ws + OFF_SF;

    float4 ci = c4[i * 64 + lane];
    float  si = sf[i];
    float acc = 0.f;
    for (int j = w; j < NC; j += 4) {
        if (j == i) continue;
        float4 cj = c4[j * 64 + lane];
        float dx = ci.x - cj.x, dy = ci.y - cj.y;
        float dz = ci.z - cj.z, dw = ci.w - cj.w;
        float ss = dx*dx + dy*dy + dz*dz + dw*dw;
        #pragma unroll
        for (int o = 32; o > 0; o >>= 1) ss += __shfl_xor(ss, o, 64);
        float m = sqrtf(ss);
        acc += cw[i * NC + j] * (si + sf[j]) / m;
    }
    __shared__ float wsum[4];
    if (lane == 0) wsum[w] = acc;
    __syncthreads();
    if (tid == 0) ws[OFF_PAIR + i] = wsum[0] + wsum[1] + wsum[2] + wsum[3];
}

__global__ __launch_bounds__(256)
void k4_final(const float* __restrict__ ws, float* __restrict__ out)
{
    const int t = threadIdx.x;   // 256 threads
    float a = ws[OFF_ABS + t];
    float p = (t < 64) ? ws[OFF_PAIR + t] : 0.f;
    #pragma unroll
    for (int o = 32; o > 0; o >>= 1) {
        a += __shfl_xor(a, o, 64);
        p += __shfl_xor(p, o, 64);
    }
    __shared__ float ra[4], rp[4];
    if ((t & 63) == 0) { ra[t >> 6] = a; rp[t >> 6] = p; }
    __syncthreads();
    if (t == 0) {
        float pair_sum = rp[0] + rp[1] + rp[2] + rp[3];
        float abs_sum  = ra[0] + ra[1] + ra[2] + ra[3];
        out[0] = pair_sum / 64.0f * 63.0f + abs_sum * 1e-6f;
    }
}

extern "C" void kernel_launch(void* const* d_in, const int* in_sizes, int n_in,
                              void* d_out, int out_size, void* d_ws, size_t ws_size,
                              hipStream_t stream)
{
    const float* pred  = (const float*)d_in[0];
    const float* cent  = (const float*)d_in[1];
    const float* dist  = (const float*)d_in[2];
    const float* count = (const float*)d_in[3];
    const float* cw    = (const float*)d_in[4];
    const int*   tgt   = (const int*)d_in[5];
    float* ws  = (float*)d_ws;
    float* out = (float*)d_out;

    long ws_f  = (long)(ws_size / sizeof(float));
    long avail = ws_f - OFF_PART;
    int P = (avail >= (long)NBLK * CD) ? NBLK : 0;

    // zero atomic regions: A (fallback acc) + B (s_part)
    hipMemsetAsync(d_ws, 0, (size_t)(OFF_S + NBLK * 64) * sizeof(float), stream);

    k1_main<<<NBLK, T1, 0, stream>>>(pred, cent, count, tgt, ws, P);
    k2_reduce<<<256, 256, 0, stream>>>(cent, count, dist, ws, P);
    k3_pairs<<<NC, 256, 0, stream>>>(cw, ws);
    k4_final<<<1, 256, 0, stream>>>(ws, out);
}

// Round 3
// 376.695 us; speedup vs baseline: 1.1598x; 1.0244x over previous
//
#include <hip/hip_runtime.h>
#include <math.h>

#define NROWS 262144
#define DIM   256
#define NC    64
#define CD    (NC*DIM)       // 16384 floats = 64 KB
#define T1    512
#define NBLK  512

// ws float-offset layout:
//  A: acc fallback [CD]      @ 0
//  B: s_part [NBLK*64]       @ 16384
//  C: cent_new [CD]          @ 49152
//  D: s_final [64]           @ 65536
//  E: abs_part [256]         @ 65600
//  F: pair_part [64]         @ 65856
//  G: partials [P*CD]        @ 65920
#define OFF_S     16384
#define OFF_CENT  49152
#define OFF_SF    65536
#define OFF_ABS   65600
#define OFF_PAIR  65856
#define OFF_PART  65920

// k1: lane = row. No cross-lane ops in the hot loop; all per-row state in
// registers. LDS accumulator layout: class c's element e (0..255) stored at
// c*256 + ((e + c) & 255)  -> bank = (e + c) & 31, ~uniform over classes.
__global__ __launch_bounds__(T1, 4)
void k1_main(const float* __restrict__ pred, const float* __restrict__ cent,
             const float* __restrict__ count, const int* __restrict__ tgt,
             float* __restrict__ ws, int P)
{
    __shared__ float acc[CD];
    const int tid = threadIdx.x;
    for (int o = tid; o < CD; o += T1) acc[o] = 0.f;

    const int wave = tid >> 6;
    const int lane = tid & 63;
    const int row  = (blockIdx.x * 8 + wave) * 64 + lane;   // this lane's row
    const int   c   = tgt[row];
    const float inv = 1.0f / count[c];
    __syncthreads();

    const float4* prow = (const float4*)pred + (size_t)row * 64;
    const float4* crow = (const float4*)cent + (size_t)c * 64;
    const int cbase = c << 8;
    float ss = 0.f;

    #pragma unroll 4
    for (int d = 0; d < 64; ++d) {
        float4 p = prow[d];
        float4 e = crow[d];
        float4 pr;
        pr.x = p.x * inv; pr.y = p.y * inv;
        pr.z = p.z * inv; pr.w = p.w * inv;
        float dx = e.x - pr.x, dy = e.y - pr.y;
        float dz = e.z - pr.z, dw = e.w - pr.w;
        ss += dx*dx + dy*dy + dz*dz + dw*dw;
        const int idx = d * 4 + c;
        unsafeAtomicAdd(&acc[cbase + ( idx      & 255)], pr.x);
        unsafeAtomicAdd(&acc[cbase + ((idx + 1) & 255)], pr.y);
        unsafeAtomicAdd(&acc[cbase + ((idx + 2) & 255)], pr.z);
        unsafeAtomicAdd(&acc[cbase + ((idx + 3) & 255)], pr.w);
    }

    // per-row vec contribution, once per lane (off critical path)
    unsafeAtomicAdd(&ws[OFF_S + blockIdx.x * 64 + c], sqrtf(ss));
    __syncthreads();

    if (P > 0) {
        float4*       dst = (float4*)(ws + OFF_PART + (size_t)blockIdx.x * CD);
        const float4* src = (const float4*)acc;
        for (int o = tid; o < CD / 4; o += T1) dst[o] = src[o];
    } else {
        for (int o = tid; o < CD; o += T1) unsafeAtomicAdd(&ws[o], acc[o]);
    }
}

__global__ __launch_bounds__(512)
void k2_reduce(const float* __restrict__ cent, const float* __restrict__ count,
               const float* __restrict__ dist, float* __restrict__ ws, int P)
{
    const int tid = threadIdx.x;              // 0..511
    const int sub = tid & 63;
    const int g   = tid >> 6;                 // 0..7
    const int o   = blockIdx.x * 64 + sub;    // storage index 0..16383

    float sum = 0.f;
    if (P > 0) {
        const float* gp = ws + OFF_PART;
        #pragma unroll 4
        for (int p = g; p < P; p += 8) sum += gp[(size_t)p * CD + o];
    } else if (g == 0) {
        sum = ws[o];
    }
    __shared__ float red[8][64];
    red[g][sub] = sum;
    __syncthreads();

    if (tid < 64) {
        float tot = 0.f;
        #pragma unroll
        for (int q = 0; q < 8; ++q) tot += red[q][tid];
        const int oo = blockIdx.x * 64 + tid;     // storage index
        const int c  = oo >> 8;
        const int s  = oo & 255;
        const int dd = (s - c + 256) & 255;       // unswizzle: orig element
        float val = cent[c * 256 + dd] + tot;     // tot is sum of pr already
        ws[OFF_CENT + c * 256 + dd] = val;
        float a = fabsf(val);
        #pragma unroll
        for (int off = 32; off > 0; off >>= 1) a += __shfl_xor(a, off, 64);
        if (tid == 0) ws[OFF_ABS + blockIdx.x] = a;
    }

    if (blockIdx.x == 0) {
        __shared__ float sred[8][64];
        float ssum = 0.f;
        #pragma unroll 4
        for (int b = g; b < NBLK; b += 8) ssum += ws[OFF_S + b * 64 + sub];
        sred[g][sub] = ssum;
        __syncthreads();
        if (tid < 64) {
            float s_tot = 0.f;
            #pragma unroll
            for (int q = 0; q < 8; ++q) s_tot += sred[q][tid];
            ws[OFF_SF + tid] = sqrtf(dist[tid] + s_tot) / count[tid];
        }
    }
}

__global__ __launch_bounds__(256)
void k3_pairs(const float* __restrict__ cw, float* __restrict__ ws)
{
    const int i    = blockIdx.x;
    const int tid  = threadIdx.x;
    const int lane = tid & 63;
    const int w    = tid >> 6;
    const float4* c4 = (const float4*)(ws + OFF_CENT);
    const float*  sf = ws + OFF_SF;

    float4 ci = c4[i * 64 + lane];
    float  si = sf[i];
    float acc = 0.f;
    for (int j = w; j < NC; j += 4) {
        if (j == i) continue;
        float4 cj = c4[j * 64 + lane];
        float dx = ci.x - cj.x, dy = ci.y - cj.y;
        float dz = ci.z - cj.z, dw = ci.w - cj.w;
        float ss = dx*dx + dy*dy + dz*dz + dw*dw;
        #pragma unroll
        for (int o = 32; o > 0; o >>= 1) ss += __shfl_xor(ss, o, 64);
        float m = sqrtf(ss);
        acc += cw[i * NC + j] * (si + sf[j]) / m;
    }
    __shared__ float wsum[4];
    if (lane == 0) wsum[w] = acc;
    __syncthreads();
    if (tid == 0) ws[OFF_PAIR + i] = wsum[0] + wsum[1] + wsum[2] + wsum[3];
}

__global__ __launch_bounds__(256)
void k4_final(const float* __restrict__ ws, float* __restrict__ out)
{
    const int t = threadIdx.x;   // 256 threads
    float a = ws[OFF_ABS + t];
    float p = (t < 64) ? ws[OFF_PAIR + t] : 0.f;
    #pragma unroll
    for (int o = 32; o > 0; o >>= 1) {
        a += __shfl_xor(a, o, 64);
        p += __shfl_xor(p, o, 64);
    }
    __shared__ float ra[4], rp[4];
    if ((t & 63) == 0) { ra[t >> 6] = a; rp[t >> 6] = p; }
    __syncthreads();
    if (t == 0) {
        float pair_sum = rp[0] + rp[1] + rp[2] + rp[3];
        float abs_sum  = ra[0] + ra[1] + ra[2] + ra[3];
        out[0] = pair_sum / 64.0f * 63.0f + abs_sum * 1e-6f;
    }
}

extern "C" void kernel_launch(void* const* d_in, const int* in_sizes, int n_in,
                              void* d_out, int out_size, void* d_ws, size_t ws_size,
                              hipStream_t stream)
{
    const float* pred  = (const float*)d_in[0];
    const float* cent  = (const float*)d_in[1];
    const float* dist  = (const float*)d_in[2];
    const float* count = (const float*)d_in[3];
    const float* cw    = (const float*)d_in[4];
    const int*   tgt   = (const int*)d_in[5];
    float* ws  = (float*)d_ws;
    float* out = (float*)d_out;

    long ws_f  = (long)(ws_size / sizeof(float));
    long avail = ws_f - OFF_PART;
    int P = (avail >= (long)NBLK * CD) ? NBLK : 0;

    // zero atomic regions: A (fallback acc) + B (s_part)
    hipMemsetAsync(d_ws, 0, (size_t)(OFF_S + NBLK * 64) * sizeof(float), stream);

    k1_main<<<NBLK, T1, 0, stream>>>(pred, cent, count, tgt, ws, P);
    k2_reduce<<<256, 512, 0, stream>>>(cent, count, dist, ws, P);
    k3_pairs<<<NC, 256, 0, stream>>>(cw, ws);
    k4_final<<<1, 256, 0, stream>>>(ws, out);
}